// Round 6
// baseline (1028.936 us; speedup 1.0000x reference)
//
#include <hip/hip_runtime.h>

#define NTOK 8192
#define DIN  1024
#define DOUT 1024
#define HDIM 4096
#define NEXP 8
#define PSTR (NTOK + 256)     // padded per-expert list stride
#define HROWS 18432           // max padded pair rows (16384 + 8*256)

typedef __attribute__((ext_vector_type(8))) short bf16x8;
typedef __attribute__((ext_vector_type(4))) float f32x4;

__device__ __forceinline__ unsigned short f2bf(float f) {
  union { float f; unsigned u; } v; v.f = f;
  unsigned u = v.u;
  unsigned r = (u + 0x7fffu + ((u >> 16) & 1u)) >> 16;  // RTNE
  return (unsigned short)r;
}

__device__ __forceinline__ void gload16(const void* g, void* l) {
  __builtin_amdgcn_global_load_lds(
      (const __attribute__((address_space(1))) unsigned int*)g,
      (__attribute__((address_space(3))) unsigned int*)l, 16, 0, 0);
}

// opaque LDS read (compiler can't alias-analyze)
__device__ __forceinline__ bf16x8 ds_read128(unsigned addr) {
  bf16x8 r;
  asm volatile("ds_read_b128 %0, %1" : "=&v"(r) : "v"(addr));
  return r;
}

#define LGKM0() asm volatile("s_waitcnt lgkmcnt(0)" ::: "memory")
#define SB0()   __builtin_amdgcn_sched_barrier(0)

// ---------------- gate: fp64 dot, scores over 8 hypercube corners, top-2 ----
__global__ void gate_kernel(const float* __restrict__ x, const float* __restrict__ Wg,
                            int* __restrict__ cnt, int* __restrict__ ptok,
                            float* __restrict__ pw) {
  const int lane = threadIdx.x & 63;
  const int t = blockIdx.x * 4 + (threadIdx.x >> 6);
  const float* xr = x + (size_t)t * DIN + lane * 16;
  const float* wr = Wg + (size_t)lane * 16 * 3;
  double d0 = 0, d1 = 0, d2 = 0;
#pragma unroll
  for (int j = 0; j < 16; j++) {
    double xv = xr[j];
    d0 += xv * wr[j * 3 + 0];
    d1 += xv * wr[j * 3 + 1];
    d2 += xv * wr[j * 3 + 2];
  }
#pragma unroll
  for (int o = 32; o > 0; o >>= 1) {
    d0 += __shfl_down(d0, o);
    d1 += __shfl_down(d1, o);
    d2 += __shfl_down(d2, o);
  }
  if (lane == 0) {
    double l0 = d0 > 0 ? d0 : 0, l1 = d1 > 0 ? d1 : 0, l2 = d2 > 0 ? d2 : 0;
    double s[NEXP];
#pragma unroll
    for (int e = 0; e < NEXP; e++)
      s[e] = ((e & 1) ? l0 : -l0) + ((e & 2) ? l1 : -l1) + ((e & 4) ? l2 : -l2);
    int e0 = 0;
    for (int e = 1; e < NEXP; e++) if (s[e] > s[e0]) e0 = e;        // ties -> lowest idx
    int e1 = -1;
    for (int e = 0; e < NEXP; e++) { if (e == e0) continue; if (e1 < 0 || s[e] > s[e1]) e1 = e; }
    double w0 = 1.0 / (1.0 + exp(s[e1] - s[e0]));  // == renormalized softmax pair
    double w1 = 1.0 - w0;
    int p0 = atomicAdd(cnt + e0, 1);
    ptok[e0 * PSTR + p0] = t; pw[e0 * PSTR + p0] = (float)w0;
    int p1 = atomicAdd(cnt + e1, 1);
    ptok[e1 * PSTR + p1] = t; pw[e1 * PSTR + p1] = (float)w1;
  }
}

// padded counts + padded global offsets
__global__ void scan_kernel(const int* __restrict__ cnt, int* __restrict__ pcnt,
                            int* __restrict__ poff) {
  if (threadIdx.x == 0) {
    int a = 0;
    for (int e = 0; e < NEXP; e++) {
      int cp = (cnt[e] + 255) & ~255;
      pcnt[e] = cp; poff[e] = a; a += cp;
    }
  }
}

// fill pad entries: token=last, w=0
__global__ void pad_kernel(const int* __restrict__ cnt, const int* __restrict__ pcnt,
                           int* __restrict__ ptok, float* __restrict__ pw) {
  int e = blockIdx.x;
  int ce = cnt[e], cp = pcnt[e];
  if (ce == 0) return;
  int last = ptok[e * PSTR + ce - 1];
  for (int p = ce + threadIdx.x; p < cp; p += 256) {
    ptok[e * PSTR + p] = last;
    pw[e * PSTR + p] = 0.f;
  }
}

// ---------------- fp32 -> bf16 elementwise --------------------------------
__global__ void cvt_bf16_kernel(const float* __restrict__ src,
                                unsigned short* __restrict__ dst, int n) {
  int i = (blockIdx.x * 256 + threadIdx.x) * 8;
  if (i >= n) return;
  float4 a = *(const float4*)(src + i);
  float4 b = *(const float4*)(src + i + 4);
  __align__(16) unsigned short t[8] = {f2bf(a.x), f2bf(a.y), f2bf(a.z), f2bf(a.w),
                                       f2bf(b.x), f2bf(b.y), f2bf(b.z), f2bf(b.w)};
  *(uint4*)(dst + i) = *(const uint4*)t;
}

// ---------------- fp32 [e][K][N] -> bf16 [e][N][K] transpose ---------------
__global__ void transpose_cvt(const float* __restrict__ src,
                              unsigned short* __restrict__ dst, int K, int N) {
  __shared__ float tile[64][65];
  const size_t base = (size_t)blockIdx.z * K * N;
  const float* s = src + base;
  unsigned short* d = dst + base;
  int n0 = blockIdx.x * 64, k0 = blockIdx.y * 64;
  for (int idx = threadIdx.x; idx < 64 * 16; idx += 256) {
    int r = idx >> 4, c4 = (idx & 15) * 4;
    float4 v = *(const float4*)(s + (size_t)(k0 + r) * N + n0 + c4);
    tile[r][c4 + 0] = v.x; tile[r][c4 + 1] = v.y;
    tile[r][c4 + 2] = v.z; tile[r][c4 + 3] = v.w;
  }
  __syncthreads();
  for (int idx = threadIdx.x; idx < 64 * 8; idx += 256) {
    int nl = idx >> 3, c8 = (idx & 7) * 8;
    __align__(16) unsigned short tmp[8];
#pragma unroll
    for (int j = 0; j < 8; j++) tmp[j] = f2bf(tile[c8 + j][nl]);
    *(uint4*)(d + (size_t)(n0 + nl) * K + k0 + c8) = *(const uint4*)tmp;
  }
}

// ==========================================================================
// 256x256xBK32 8-wave grouped GEMM, 4 LDS buffers, prefetch depth 3.
// LDS 128KB: buf b in [0,4): A 16KB @ b*32768, B 16KB @ b*32768+16384.
// Tile row stride 64B (4 chunks of 16B); chunk swizzle c' = c ^ ((row>>1)&3)
// applied as inverse-permuted GLOBAL source (gload_lds dest stays linear)
// and on the ds_read address. One s_barrier + counted vmcnt per K-tile:
//   vmcnt(8) -> barrier -> stage(t+3) -> 12 ds_read -> lgkm0 -> 32 MFMA.
// ==========================================================================

#define STAGE(tt)                                                        \
  do {                                                                   \
    unsigned bb2 = ((unsigned)(tt) & 3u) * 32768u;                       \
    int kel = (tt) * 32;                                                 \
    gload16(aptr0 + kel, dstA + bb2);                                    \
    gload16(aptr1 + kel, dstA + bb2 + 1024u);                            \
    gload16(bptr0 + kel, dstA + bb2 + 16384u);                           \
    gload16(bptr1 + kel, dstA + bb2 + 16384u + 1024u);                   \
  } while (0)

#define KLOOP(KT)                                                              \
  STAGE(0); STAGE(1); STAGE(2);                                                \
  for (int t = 0; t < (KT); t++) {                                             \
    if (t + 2 < (KT))      asm volatile("s_waitcnt vmcnt(8)" ::: "memory");    \
    else if (t + 1 < (KT)) asm volatile("s_waitcnt vmcnt(4)" ::: "memory");    \
    else                   asm volatile("s_waitcnt vmcnt(0)" ::: "memory");    \
    __builtin_amdgcn_s_barrier();                                              \
    if (t + 3 < (KT)) STAGE(t + 3);                                            \
    const unsigned bb = ((unsigned)t & 3u) * 32768u;                           \
    _Pragma("unroll") for (int am = 0; am < 8; am++)                           \
      afr[am] = ds_read128(aoff + bb + (unsigned)am * 1024u);                  \
    _Pragma("unroll") for (int an = 0; an < 4; an++)                           \
      bfr[an] = ds_read128(boff + bb + (unsigned)an * 1024u);                  \
    LGKM0(); SB0();                                                            \
    __builtin_amdgcn_s_setprio(1);                                             \
    _Pragma("unroll") for (int am = 0; am < 8; am++)                           \
      _Pragma("unroll") for (int an = 0; an < 4; an++)                         \
        acc[am][an] = __builtin_amdgcn_mfma_f32_16x16x32_bf16(                 \
            afr[am], bfr[an], acc[am][an], 0, 0, 0);                           \
    __builtin_amdgcn_s_setprio(0);                                             \
    SB0();                                                                     \
  }

// per-thread staging geometry (shared by both kernels)
#define STAGE_GEOM()                                                           \
  const int tid = threadIdx.x;                                                 \
  const int lane = tid & 63;                                                   \
  const int wid = tid >> 6;                                                    \
  const int wm = wid >> 2, wn = wid & 3;                                       \
  const int ch0 = wid * 128 + lane;      /* chunk ids staged by this thread */ \
  const int ch1 = ch0 + 64;                                                    \
  const int row0 = ch0 >> 2, row1 = ch1 >> 2;                                  \
  const int pe0 = ((ch0 & 3) ^ ((row0 >> 1) & 3)) * 8;                         \
  const int pe1 = ((ch1 & 3) ^ ((row1 >> 1) & 3)) * 8;                         \
  char* dstA = lds + (unsigned)(wid * 2048 + lane * 16);                       \
  const int fr = lane & 15;                                                    \
  const int hi = lane >> 4;                                                    \
  const unsigned koff = (unsigned)(((hi ^ ((fr >> 1) & 3)) << 4));             \
  const unsigned ldsbase = (unsigned)(size_t)(void*)lds;                       \
  const unsigned aoff = ldsbase + (unsigned)((wm * 128 + fr) * 64) + koff;     \
  const unsigned boff = ldsbase + 16384u + (unsigned)((wn * 64 + fr) * 64) + koff;

// ---------------- grouped GEMM1: h = relu(x @ W1[e] + b1[e]) ---------------
__global__ __launch_bounds__(512, 1) void gemm1_kernel(
    const unsigned short* __restrict__ xbf,   // [NTOK][DIN]
    const unsigned short* __restrict__ w1t,   // [E][HDIM][DIN]
    const float* __restrict__ b1,             // [E][HDIM]
    const int* __restrict__ pcnt, const int* __restrict__ poff,
    const int* __restrict__ ptok,
    unsigned short* __restrict__ h)           // [HROWS][HDIM] padded
{
  extern __shared__ char lds[];
  const int bid = blockIdx.x;
  const int e = bid & 7;
  const int cp = pcnt[e];
  const int j = bid >> 3;
  if (j >= (cp >> 8) * 16) return;
  const int mt = j >> 4;
  const int nt = j & 15;
  const int m0 = mt << 8;
  const int n0 = nt << 8;
  const int oe = poff[e];

  STAGE_GEOM();

  const unsigned short* wb = w1t + (size_t)e * HDIM * DIN;
  const int ta0 = ptok[e * PSTR + m0 + row0];
  const int ta1 = ptok[e * PSTR + m0 + row1];
  const unsigned short* aptr0 = xbf + (size_t)ta0 * DIN + pe0;
  const unsigned short* aptr1 = xbf + (size_t)ta1 * DIN + pe1;
  const unsigned short* bptr0 = wb + (size_t)(n0 + row0) * DIN + pe0;
  const unsigned short* bptr1 = wb + (size_t)(n0 + row1) * DIN + pe1;

  f32x4 acc[8][4] = {};
  bf16x8 afr[8], bfr[4];

  KLOOP(DIN / 32);

  // epilogue: bias + relu + bf16 store (all rows exist: padded tiles are full)
#pragma unroll
  for (int am = 0; am < 8; am++) {
    int rbase = wm * 128 + am * 16 + hi * 4;
#pragma unroll
    for (int r = 0; r < 4; r++) {
      size_t hoff = (size_t)(oe + m0 + rbase + r) * HDIM;
#pragma unroll
      for (int an = 0; an < 4; an++) {
        int col = n0 + wn * 64 + an * 16 + fr;
        float v = acc[am][an][r] + b1[e * HDIM + col];
        h[hoff + col] = f2bf(v > 0.f ? v : 0.f);
      }
    }
  }
}

// ---------------- grouped GEMM2: out += w * (h @ W2[e] + b2[e]) ------------
// split-K x2: kh in {0,1}, K-half = 2048; bias applied in kh==0 only.
__global__ __launch_bounds__(512, 1) void gemm2_kernel(
    const unsigned short* __restrict__ h,     // [HROWS][HDIM] padded
    const unsigned short* __restrict__ w2t,   // [E][DOUT][HDIM]
    const float* __restrict__ b2,             // [E][DOUT]
    const int* __restrict__ pcnt, const int* __restrict__ poff,
    const int* __restrict__ ptok, const float* __restrict__ pw,
    float* __restrict__ out)                  // [NTOK][DOUT]
{
  extern __shared__ char lds[];
  const int bid = blockIdx.x;
  const int e = bid & 7;
  const int cp = pcnt[e];
  const int j = bid >> 3;
  if (j >= (cp >> 8) * 8) return;
  const int mt = j >> 3;
  const int r2 = j & 7;
  const int nt = r2 >> 1;
  const int kh = r2 & 1;
  const int m0 = mt << 8;
  const int n0 = nt << 8;
  const int oe = poff[e];
  const int kbase = kh * 2048;

  STAGE_GEOM();

  const unsigned short* wb = w2t + (size_t)e * DOUT * HDIM;
  const unsigned short* aptr0 = h + (size_t)(oe + m0 + row0) * HDIM + kbase + pe0;
  const unsigned short* aptr1 = h + (size_t)(oe + m0 + row1) * HDIM + kbase + pe1;
  const unsigned short* bptr0 = wb + (size_t)(n0 + row0) * HDIM + kbase + pe0;
  const unsigned short* bptr1 = wb + (size_t)(n0 + row1) * HDIM + kbase + pe1;

  f32x4 acc[8][4] = {};
  bf16x8 afr[8], bfr[4];

  KLOOP(2048 / 32);

  // epilogue: weighted atomic accumulate; pads (w==0) skipped
#pragma unroll
  for (int am = 0; am < 8; am++) {
    int rbase = wm * 128 + am * 16 + hi * 4;
#pragma unroll
    for (int r = 0; r < 4; r++) {
      int pidx = e * PSTR + m0 + rbase + r;
      int token = ptok[pidx];
      float w = pw[pidx];
      if (w == 0.f) continue;
#pragma unroll
      for (int an = 0; an < 4; an++) {
        int col = n0 + wn * 64 + an * 16 + fr;
        float v = (acc[am][an][r] + (kh == 0 ? b2[e * DOUT + col] : 0.f)) * w;
        atomicAdd(out + (size_t)token * DOUT + col, v);
      }
    }
  }
}

extern "C" void kernel_launch(void* const* d_in, const int* in_sizes, int n_in,
                              void* d_out, int out_size, void* d_ws, size_t ws_size,
                              hipStream_t stream) {
  const float* x  = (const float*)d_in[0];
  const float* Wg = (const float*)d_in[1];
  const float* W1 = (const float*)d_in[2];
  const float* b1 = (const float*)d_in[3];
  const float* W2 = (const float*)d_in[4];
  const float* b2 = (const float*)d_in[5];
  float* out = (float*)d_out;

  char* ws = (char*)d_ws;
  size_t o = 0;
  auto nxt = [&](size_t b) { char* p = ws + o; o = (o + b + 255) & ~(size_t)255; return p; };
  int* cnt = (int*)nxt(64);
  int* pcnt = (int*)nxt(64);
  int* poff = (int*)nxt(64);
  int* ptok = (int*)nxt((size_t)NEXP * PSTR * 4);
  float* pw = (float*)nxt((size_t)NEXP * PSTR * 4);
  unsigned short* xbf = (unsigned short*)nxt((size_t)NTOK * DIN * 2);
  unsigned short* w1t = (unsigned short*)nxt((size_t)NEXP * HDIM * DIN * 2);
  unsigned short* w2t = (unsigned short*)nxt((size_t)NEXP * DOUT * HDIM * 2);
  unsigned short* hbuf = (unsigned short*)nxt((size_t)HROWS * HDIM * 2);

  hipFuncSetAttribute((const void*)gemm1_kernel,
                      hipFuncAttributeMaxDynamicSharedMemorySize, 131072);
  hipFuncSetAttribute((const void*)gemm2_kernel,
                      hipFuncAttributeMaxDynamicSharedMemorySize, 131072);

  hipMemsetAsync(cnt, 0, 64, stream);
  hipMemsetAsync(out, 0, (size_t)NTOK * DOUT * 4, stream);

  gate_kernel<<<NTOK / 4, 256, 0, stream>>>(x, Wg, cnt, ptok, pw);
  scan_kernel<<<1, 64, 0, stream>>>(cnt, pcnt, poff);
  pad_kernel<<<NEXP, 256, 0, stream>>>(cnt, pcnt, ptok, pw);
  cvt_bf16_kernel<<<(NTOK * DIN / 8) / 256, 256, 0, stream>>>(x, xbf, NTOK * DIN);
  transpose_cvt<<<dim3(HDIM / 64, DIN / 64, NEXP), 256, 0, stream>>>(W1, w1t, DIN, HDIM);
  transpose_cvt<<<dim3(DOUT / 64, HDIM / 64, NEXP), 256, 0, stream>>>(W2, w2t, HDIM, DOUT);

  // flat padded grids: e = bid&7, j = bid>>3 (worst-case sized; extras exit)
  gemm1_kernel<<<8 * 33 * 16, 512, 131072, stream>>>(
      xbf, w1t, b1, pcnt, poff, ptok, hbuf);
  gemm2_kernel<<<8 * 33 * 8, 512, 131072, stream>>>(
      hbuf, w2t, b2, pcnt, poff, ptok, pw, out);
}

// Round 7
// 945.074 us; speedup vs baseline: 1.0887x; 1.0887x over previous
//
#include <hip/hip_runtime.h>

#define NTOK 8192
#define DIN  1024
#define DOUT 1024
#define HDIM 4096
#define NEXP 8
#define PSTR (NTOK + 256)     // padded per-expert list stride
#define HROWS 18432           // max padded pair rows (16384 + 8*256)

typedef __attribute__((ext_vector_type(8))) short bf16x8;
typedef __attribute__((ext_vector_type(4))) float f32x4;

__device__ __forceinline__ unsigned short f2bf(float f) {
  union { float f; unsigned u; } v; v.f = f;
  unsigned u = v.u;
  unsigned r = (u + 0x7fffu + ((u >> 16) & 1u)) >> 16;  // RTNE
  return (unsigned short)r;
}

#define LGKM0() asm volatile("s_waitcnt lgkmcnt(0)" ::: "memory")
#define SB0()   __builtin_amdgcn_sched_barrier(0)

// ---------------- gate: fp64 dot, scores over 8 hypercube corners, top-2 ----
__global__ void gate_kernel(const float* __restrict__ x, const float* __restrict__ Wg,
                            int* __restrict__ cnt, int* __restrict__ ptok,
                            float* __restrict__ pw) {
  const int lane = threadIdx.x & 63;
  const int t = blockIdx.x * 4 + (threadIdx.x >> 6);
  const float* xr = x + (size_t)t * DIN + lane * 16;
  const float* wr = Wg + (size_t)lane * 16 * 3;
  double d0 = 0, d1 = 0, d2 = 0;
#pragma unroll
  for (int j = 0; j < 16; j++) {
    double xv = xr[j];
    d0 += xv * wr[j * 3 + 0];
    d1 += xv * wr[j * 3 + 1];
    d2 += xv * wr[j * 3 + 2];
  }
#pragma unroll
  for (int o = 32; o > 0; o >>= 1) {
    d0 += __shfl_down(d0, o);
    d1 += __shfl_down(d1, o);
    d2 += __shfl_down(d2, o);
  }
  if (lane == 0) {
    double l0 = d0 > 0 ? d0 : 0, l1 = d1 > 0 ? d1 : 0, l2 = d2 > 0 ? d2 : 0;
    double s[NEXP];
#pragma unroll
    for (int e = 0; e < NEXP; e++)
      s[e] = ((e & 1) ? l0 : -l0) + ((e & 2) ? l1 : -l1) + ((e & 4) ? l2 : -l2);
    int e0 = 0;
    for (int e = 1; e < NEXP; e++) if (s[e] > s[e0]) e0 = e;        // ties -> lowest idx
    int e1 = -1;
    for (int e = 0; e < NEXP; e++) { if (e == e0) continue; if (e1 < 0 || s[e] > s[e1]) e1 = e; }
    double w0 = 1.0 / (1.0 + exp(s[e1] - s[e0]));  // == renormalized softmax pair
    double w1 = 1.0 - w0;
    int p0 = atomicAdd(cnt + e0, 1);
    ptok[e0 * PSTR + p0] = t; pw[e0 * PSTR + p0] = (float)w0;
    int p1 = atomicAdd(cnt + e1, 1);
    ptok[e1 * PSTR + p1] = t; pw[e1 * PSTR + p1] = (float)w1;
  }
}

// padded counts + padded global offsets
__global__ void scan_kernel(const int* __restrict__ cnt, int* __restrict__ pcnt,
                            int* __restrict__ poff) {
  if (threadIdx.x == 0) {
    int a = 0;
    for (int e = 0; e < NEXP; e++) {
      int cp = (cnt[e] + 255) & ~255;
      pcnt[e] = cp; poff[e] = a; a += cp;
    }
  }
}

// fill pad entries: token=last, w=0
__global__ void pad_kernel(const int* __restrict__ cnt, const int* __restrict__ pcnt,
                           int* __restrict__ ptok, float* __restrict__ pw) {
  int e = blockIdx.x;
  int ce = cnt[e], cp = pcnt[e];
  if (ce == 0) return;
  int last = ptok[e * PSTR + ce - 1];
  for (int p = ce + threadIdx.x; p < cp; p += 256) {
    ptok[e * PSTR + p] = last;
    pw[e * PSTR + p] = 0.f;
  }
}

// ---------------- fp32 -> bf16 elementwise --------------------------------
__global__ void cvt_bf16_kernel(const float* __restrict__ src,
                                unsigned short* __restrict__ dst, int n) {
  int i = (blockIdx.x * 256 + threadIdx.x) * 8;
  if (i >= n) return;
  float4 a = *(const float4*)(src + i);
  float4 b = *(const float4*)(src + i + 4);
  __align__(16) unsigned short t[8] = {f2bf(a.x), f2bf(a.y), f2bf(a.z), f2bf(a.w),
                                       f2bf(b.x), f2bf(b.y), f2bf(b.z), f2bf(b.w)};
  *(uint4*)(dst + i) = *(const uint4*)t;
}

// ---------------- fp32 [e][K][N] -> bf16 [e][N][K] transpose ---------------
__global__ void transpose_cvt(const float* __restrict__ src,
                              unsigned short* __restrict__ dst, int K, int N) {
  __shared__ float tile[64][65];
  const size_t base = (size_t)blockIdx.z * K * N;
  const float* s = src + base;
  unsigned short* d = dst + base;
  int n0 = blockIdx.x * 64, k0 = blockIdx.y * 64;
  for (int idx = threadIdx.x; idx < 64 * 16; idx += 256) {
    int r = idx >> 4, c4 = (idx & 15) * 4;
    float4 v = *(const float4*)(s + (size_t)(k0 + r) * N + n0 + c4);
    tile[r][c4 + 0] = v.x; tile[r][c4 + 1] = v.y;
    tile[r][c4 + 2] = v.z; tile[r][c4 + 3] = v.w;
  }
  __syncthreads();
  for (int idx = threadIdx.x; idx < 64 * 8; idx += 256) {
    int nl = idx >> 3, c8 = (idx & 7) * 8;
    __align__(16) unsigned short tmp[8];
#pragma unroll
    for (int j = 0; j < 8; j++) tmp[j] = f2bf(tile[c8 + j][nl]);
    *(uint4*)(d + (size_t)(n0 + nl) * K + k0 + c8) = *(const uint4*)tmp;
  }
}

// ==========================================================================
// 256x256xBK64 8-wave grouped GEMM, REG-STAGED (global->VGPR->LDS), single
// 64KB LDS buffer. Async split: loads for tile t+1 issue BEFORE compute(t)
// (HBM/L3 latency hides under MFMA), ds_writes land after the post-compute
// barrier. Swizzle: chunk (row, kc) stored at elem row*64 + ((kc^(row&7))*8)
// -> measured 0 bank conflicts (r5/r6). No global_load_lds anywhere.
// ==========================================================================

#define LOADT(koffe)                                                           \
  pa0 = *(const uint4*)(ga0 + (koffe)); pa1 = *(const uint4*)(ga1 + (koffe));  \
  pa2 = *(const uint4*)(ga2 + (koffe)); pa3 = *(const uint4*)(ga3 + (koffe));  \
  pb0 = *(const uint4*)(gb0 + (koffe)); pb1 = *(const uint4*)(gb1 + (koffe));  \
  pb2 = *(const uint4*)(gb2 + (koffe)); pb3 = *(const uint4*)(gb3 + (koffe));

#define WRITET()                                                               \
  *(uint4*)(As + wbase)         = pa0;  *(uint4*)(As + wbase + 4096)  = pa1;   \
  *(uint4*)(As + wbase + 8192)  = pa2;  *(uint4*)(As + wbase + 12288) = pa3;   \
  *(uint4*)(Bs + wbase)         = pb0;  *(uint4*)(Bs + wbase + 4096)  = pb1;   \
  *(uint4*)(Bs + wbase + 8192)  = pb2;  *(uint4*)(Bs + wbase + 12288) = pb3;

#define COMPUTET()                                                             \
  _Pragma("unroll") for (int ks = 0; ks < 2; ks++) {                           \
    bf16x8 afr[8], bfr[4];                                                     \
    _Pragma("unroll") for (int am = 0; am < 8; am++)                           \
      afr[am] = *(const bf16x8*)(As + aoffb + am * 1024 + koffr[ks]);          \
    _Pragma("unroll") for (int an = 0; an < 4; an++)                           \
      bfr[an] = *(const bf16x8*)(Bs + boffb + an * 1024 + koffr[ks]);          \
    __builtin_amdgcn_s_setprio(1);                                             \
    _Pragma("unroll") for (int am = 0; am < 8; am++)                           \
      _Pragma("unroll") for (int an = 0; an < 4; an++)                         \
        acc[am][an] = __builtin_amdgcn_mfma_f32_16x16x32_bf16(                 \
            afr[am], bfr[an], acc[am][an], 0, 0, 0);                           \
    __builtin_amdgcn_s_setprio(0);                                             \
  }

#define KLOOP(KT)                                                              \
  LOADT(0);                                                                    \
  WRITET();                                                                    \
  LGKM0();                                                                     \
  __builtin_amdgcn_s_barrier();                                                \
  for (int t = 0; t < (KT); t++) {                                             \
    if (t + 1 < (KT)) { LOADT((t + 1) * 64); }                                 \
    SB0();                                                                     \
    COMPUTET();                                                                \
    SB0();                                                                     \
    __builtin_amdgcn_s_barrier();   /* all waves done reading buffer */        \
    if (t + 1 < (KT)) {                                                        \
      WRITET();                     /* compiler inserts vmcnt waits */         \
      LGKM0();                                                                 \
      __builtin_amdgcn_s_barrier(); /* buffer ready for t+1 */                 \
    }                                                                          \
  }

// shared geometry: 8 waves as 2(wm) x 4(wn); thread stages rows rth+64i, chunk kc
#define GEOM()                                                                 \
  const int tid = threadIdx.x;                                                 \
  const int lane = tid & 63;                                                   \
  const int wid = tid >> 6;                                                    \
  const int wm = wid >> 2, wn = wid & 3;                                       \
  const int fr = lane & 15, hi = lane >> 4;                                    \
  const int rth = tid >> 3;                                                    \
  const int kc = tid & 7;                                                      \
  const unsigned wbase = (unsigned)(rth * 64 + ((kc ^ (rth & 7)) * 8));        \
  const unsigned aoffb = (unsigned)((wm * 128 + fr) * 64);                     \
  const unsigned boffb = (unsigned)((wn * 64 + fr) * 64);                      \
  const unsigned koffr[2] = {(unsigned)(((0 * 4 + hi) ^ (fr & 7)) * 8),        \
                             (unsigned)(((1 * 4 + hi) ^ (fr & 7)) * 8)};

// ---------------- grouped GEMM1: h = relu(x @ W1[e] + b1[e]) ---------------
__global__ __launch_bounds__(512, 1) void gemm1_kernel(
    const unsigned short* __restrict__ xbf,   // [NTOK][DIN]
    const unsigned short* __restrict__ w1t,   // [E][HDIM][DIN]
    const float* __restrict__ b1,             // [E][HDIM]
    const int* __restrict__ pcnt, const int* __restrict__ poff,
    const int* __restrict__ ptok,
    unsigned short* __restrict__ h)           // [HROWS][HDIM] padded
{
  __shared__ __align__(16) unsigned short As[256 * 64];
  __shared__ __align__(16) unsigned short Bs[256 * 64];
  const int bid = blockIdx.x;
  const int e = bid & 7;                      // expert <-> XCD colocation
  const int cp = pcnt[e];
  const int j = bid >> 3;
  if (j >= (cp >> 8) * 16) return;
  const int mt = j >> 4, nt = j & 15;
  const int m0 = mt << 8, n0 = nt << 8;
  const int oe = poff[e];

  GEOM();

  const unsigned short* wbp = w1t + (size_t)e * HDIM * DIN;
  const int ta0 = ptok[e * PSTR + m0 + rth];
  const int ta1 = ptok[e * PSTR + m0 + rth + 64];
  const int ta2 = ptok[e * PSTR + m0 + rth + 128];
  const int ta3 = ptok[e * PSTR + m0 + rth + 192];
  const unsigned short* ga0 = xbf + (size_t)ta0 * DIN + kc * 8;
  const unsigned short* ga1 = xbf + (size_t)ta1 * DIN + kc * 8;
  const unsigned short* ga2 = xbf + (size_t)ta2 * DIN + kc * 8;
  const unsigned short* ga3 = xbf + (size_t)ta3 * DIN + kc * 8;
  const unsigned short* gb0 = wbp + (size_t)(n0 + rth) * DIN + kc * 8;
  const unsigned short* gb1 = wbp + (size_t)(n0 + rth + 64) * DIN + kc * 8;
  const unsigned short* gb2 = wbp + (size_t)(n0 + rth + 128) * DIN + kc * 8;
  const unsigned short* gb3 = wbp + (size_t)(n0 + rth + 192) * DIN + kc * 8;

  f32x4 acc[8][4] = {};
  uint4 pa0, pa1, pa2, pa3, pb0, pb1, pb2, pb3;

  KLOOP(DIN / 64);

  // epilogue: bias + relu + bf16 store (padded tiles are full)
#pragma unroll
  for (int am = 0; am < 8; am++) {
    int rbase = wm * 128 + am * 16 + hi * 4;
#pragma unroll
    for (int r = 0; r < 4; r++) {
      size_t hoff = (size_t)(oe + m0 + rbase + r) * HDIM;
#pragma unroll
      for (int an = 0; an < 4; an++) {
        int col = n0 + wn * 64 + an * 16 + fr;
        float v = acc[am][an][r] + b1[e * HDIM + col];
        h[hoff + col] = f2bf(v > 0.f ? v : 0.f);
      }
    }
  }
}

// ---------------- grouped GEMM2: out += w * (h @ W2[e] + b2[e]) ------------
__global__ __launch_bounds__(512, 1) void gemm2_kernel(
    const unsigned short* __restrict__ h,     // [HROWS][HDIM] padded
    const unsigned short* __restrict__ w2t,   // [E][DOUT][HDIM]
    const float* __restrict__ b2,             // [E][DOUT]
    const int* __restrict__ pcnt, const int* __restrict__ poff,
    const int* __restrict__ ptok, const float* __restrict__ pw,
    float* __restrict__ out)                  // [NTOK][DOUT]
{
  __shared__ __align__(16) unsigned short As[256 * 64];
  __shared__ __align__(16) unsigned short Bs[256 * 64];
  const int bid = blockIdx.x;
  const int e = bid & 7;
  const int cp = pcnt[e];
  const int j = bid >> 3;
  if (j >= (cp >> 8) * 4) return;
  const int mt = j >> 2, nt = j & 3;
  const int m0 = mt << 8, n0 = nt << 8;
  const int oe = poff[e];

  GEOM();

  const unsigned short* wbp = w2t + (size_t)e * DOUT * HDIM;
  const unsigned short* ga0 = h + (size_t)(oe + m0 + rth) * HDIM + kc * 8;
  const unsigned short* ga1 = h + (size_t)(oe + m0 + rth + 64) * HDIM + kc * 8;
  const unsigned short* ga2 = h + (size_t)(oe + m0 + rth + 128) * HDIM + kc * 8;
  const unsigned short* ga3 = h + (size_t)(oe + m0 + rth + 192) * HDIM + kc * 8;
  const unsigned short* gb0 = wbp + (size_t)(n0 + rth) * HDIM + kc * 8;
  const unsigned short* gb1 = wbp + (size_t)(n0 + rth + 64) * HDIM + kc * 8;
  const unsigned short* gb2 = wbp + (size_t)(n0 + rth + 128) * HDIM + kc * 8;
  const unsigned short* gb3 = wbp + (size_t)(n0 + rth + 192) * HDIM + kc * 8;

  f32x4 acc[8][4] = {};
  uint4 pa0, pa1, pa2, pa3, pb0, pb1, pb2, pb3;

  KLOOP(HDIM / 64);

  // epilogue: weighted atomic accumulate; pads (w==0) skipped
#pragma unroll
  for (int am = 0; am < 8; am++) {
    int rbase = wm * 128 + am * 16 + hi * 4;
#pragma unroll
    for (int r = 0; r < 4; r++) {
      int pidx = e * PSTR + m0 + rbase + r;
      int token = ptok[pidx];
      float w = pw[pidx];
      if (w == 0.f) continue;
#pragma unroll
      for (int an = 0; an < 4; an++) {
        int col = n0 + wn * 64 + an * 16 + fr;
        float v = (acc[am][an][r] + b2[e * DOUT + col]) * w;
        atomicAdd(out + (size_t)token * DOUT + col, v);
      }
    }
  }
}

extern "C" void kernel_launch(void* const* d_in, const int* in_sizes, int n_in,
                              void* d_out, int out_size, void* d_ws, size_t ws_size,
                              hipStream_t stream) {
  const float* x  = (const float*)d_in[0];
  const float* Wg = (const float*)d_in[1];
  const float* W1 = (const float*)d_in[2];
  const float* b1 = (const float*)d_in[3];
  const float* W2 = (const float*)d_in[4];
  const float* b2 = (const float*)d_in[5];
  float* out = (float*)d_out;

  char* ws = (char*)d_ws;
  size_t o = 0;
  auto nxt = [&](size_t b) { char* p = ws + o; o = (o + b + 255) & ~(size_t)255; return p; };
  int* cnt = (int*)nxt(64);
  int* pcnt = (int*)nxt(64);
  int* poff = (int*)nxt(64);
  int* ptok = (int*)nxt((size_t)NEXP * PSTR * 4);
  float* pw = (float*)nxt((size_t)NEXP * PSTR * 4);
  unsigned short* xbf = (unsigned short*)nxt((size_t)NTOK * DIN * 2);
  unsigned short* w1t = (unsigned short*)nxt((size_t)NEXP * HDIM * DIN * 2);
  unsigned short* w2t = (unsigned short*)nxt((size_t)NEXP * DOUT * HDIM * 2);
  unsigned short* hbuf = (unsigned short*)nxt((size_t)HROWS * HDIM * 2);

  hipMemsetAsync(cnt, 0, 64, stream);
  hipMemsetAsync(out, 0, (size_t)NTOK * DOUT * 4, stream);

  gate_kernel<<<NTOK / 4, 256, 0, stream>>>(x, Wg, cnt, ptok, pw);
  scan_kernel<<<1, 64, 0, stream>>>(cnt, pcnt, poff);
  pad_kernel<<<NEXP, 256, 0, stream>>>(cnt, pcnt, ptok, pw);
  cvt_bf16_kernel<<<(NTOK * DIN / 8) / 256, 256, 0, stream>>>(x, xbf, NTOK * DIN);
  transpose_cvt<<<dim3(HDIM / 64, DIN / 64, NEXP), 256, 0, stream>>>(W1, w1t, DIN, HDIM);
  transpose_cvt<<<dim3(DOUT / 64, HDIM / 64, NEXP), 256, 0, stream>>>(W2, w2t, HDIM, DOUT);

  // flat padded grids: e = bid&7 (XCD colocation), j = bid>>3; extras exit.
  gemm1_kernel<<<8 * 33 * 16, 512, 0, stream>>>(
      xbf, w1t, b1, pcnt, poff, ptok, hbuf);
  gemm2_kernel<<<8 * 33 * 4, 512, 0, stream>>>(
      hbuf, w2t, b2, pcnt, poff, ptok, pw, out);
}